// Round 1
// baseline (7959.540 us; speedup 1.0000x reference)
//
#include <hip/hip_runtime.h>
#include <math.h>

#define DIMW   1024   // model dim
#define HD     1024   // n_heads * head_dim
#define NH     16
#define HDIM   64
#define SEQ    2048
#define BATCH  2
#define MTOT   (BATCH*SEQ)   // 4096

// ---------------- fp32 tiled GEMM: C[M,N] = A[M,K] @ B[K,N] (+ bias) --------
#define BM 64
#define BN 64
#define BK 16

__global__ __launch_bounds__(256) void gemm_bias_kernel(
    const float* __restrict__ A, const float* __restrict__ B,
    const float* __restrict__ bias, float* __restrict__ C,
    int M, int N, int K)
{
    __shared__ float As[BK][BM + 1];   // +1 pad: kills 16-way write conflict
    __shared__ float Bs[BK][BN];

    const int tid = threadIdx.x;
    const int tx  = tid & 15;          // 0..15 -> N micro
    const int ty  = tid >> 4;          // 0..15 -> M micro
    const int n0  = blockIdx.x * BN;
    const int m0  = blockIdx.y * BM;

    float acc[4][4] = {};

    for (int k0 = 0; k0 < K; k0 += BK) {
        // A tile 64x16: k = tid%16 (coalesced 64B runs), m = tid/16 + 16*j
        {
            const int k     = tid & 15;
            const int mbase = tid >> 4;
            #pragma unroll
            for (int j = 0; j < 4; ++j) {
                const int m = mbase + 16 * j;
                As[k][m] = A[(size_t)(m0 + m) * K + (k0 + k)];
            }
        }
        // B tile 16x64: n = tid%64 (coalesced 256B runs), k = tid/64 + 4*j
        {
            const int n     = tid & 63;
            const int kbase = tid >> 6;
            #pragma unroll
            for (int j = 0; j < 4; ++j) {
                const int k = kbase + 4 * j;
                Bs[k][n] = B[(size_t)(k0 + k) * N + (n0 + n)];
            }
        }
        __syncthreads();

        #pragma unroll
        for (int kk = 0; kk < BK; ++kk) {
            float a[4], b[4];
            #pragma unroll
            for (int i = 0; i < 4; ++i) a[i] = As[kk][ty * 4 + i];
            #pragma unroll
            for (int j = 0; j < 4; ++j) b[j] = Bs[kk][tx * 4 + j];
            #pragma unroll
            for (int i = 0; i < 4; ++i)
                #pragma unroll
                for (int j = 0; j < 4; ++j)
                    acc[i][j] += a[i] * b[j];
        }
        __syncthreads();
    }

    #pragma unroll
    for (int i = 0; i < 4; ++i) {
        const int m = m0 + ty * 4 + i;
        #pragma unroll
        for (int j = 0; j < 4; ++j) {
            const int n = n0 + tx * 4 + j;
            float v = acc[i][j];
            if (bias) v += bias[n];
            C[(size_t)m * N + n] = v;
        }
    }
}

// ---------------- attention: 1 block per (b, h, query-row) ------------------
// scores in LDS (2048 f32), block max/sum reduce, then PV with 4-way key split
__global__ __launch_bounds__(256) void attn_kernel(
    const float* __restrict__ Q, const float* __restrict__ K,
    const float* __restrict__ V, float* __restrict__ Aout)
{
    __shared__ float sc[SEQ];
    __shared__ float qs[HDIM];
    __shared__ float red[256];

    const int tid = threadIdx.x;
    const int i   = blockIdx.x;
    const int h   = blockIdx.y;
    const int b   = blockIdx.z;

    const size_t qoff = ((size_t)(b * SEQ + i)) * HD + h * HDIM;
    if (tid < HDIM) qs[tid] = Q[qoff + tid];
    __syncthreads();

    const float scale = 0.125f;  // 1/sqrt(64)

    // scores + local max
    float lmax = -1e30f;
    for (int k = tid; k < SEQ; k += 256) {
        const float* kp = K + ((size_t)(b * SEQ + k)) * HD + h * HDIM;
        float s = 0.f;
        #pragma unroll
        for (int d = 0; d < HDIM; ++d) s += qs[d] * kp[d];
        s *= scale;
        sc[k] = s;
        lmax = fmaxf(lmax, s);
    }
    red[tid] = lmax;
    __syncthreads();
    for (int off = 128; off > 0; off >>= 1) {
        if (tid < off) red[tid] = fmaxf(red[tid], red[tid + off]);
        __syncthreads();
    }
    const float mx = red[0];
    __syncthreads();

    // exp + sum
    float lsum = 0.f;
    for (int k = tid; k < SEQ; k += 256) {
        const float e = __expf(sc[k] - mx);
        sc[k] = e;
        lsum += e;
    }
    red[tid] = lsum;
    __syncthreads();
    for (int off = 128; off > 0; off >>= 1) {
        if (tid < off) red[tid] += red[tid + off];
        __syncthreads();
    }
    const float inv = 1.f / red[0];
    __syncthreads();

    // PV: thread (d = tid&63, chunk = tid>>6) accumulates 512 keys
    const int d = tid & 63;
    const int c = tid >> 6;
    float acc = 0.f;
    const int kbeg = c * (SEQ / 4), kend = kbeg + (SEQ / 4);
    for (int k = kbeg; k < kend; ++k)
        acc += sc[k] * V[((size_t)(b * SEQ + k)) * HD + h * HDIM + d];
    red[tid] = acc;
    __syncthreads();
    if (tid < 64) {
        const float r = (red[tid] + red[tid + 64]) + (red[tid + 128] + red[tid + 192]);
        // writes exactly the Q slice this block already consumed (A aliases Q)
        Aout[qoff + tid] = r * inv;
    }
}

// ---------------------------------------------------------------------------
extern "C" void kernel_launch(void* const* d_in, const int* in_sizes, int n_in,
                              void* d_out, int out_size, void* d_ws, size_t ws_size,
                              hipStream_t stream)
{
    const float* x  = (const float*)d_in[0];
    const float* Wq = (const float*)d_in[1];
    const float* Wk = (const float*)d_in[2];
    const float* Wv = (const float*)d_in[3];
    const float* Wo = (const float*)d_in[4];
    const float* bo = (const float*)d_in[5];
    float* out = (float*)d_out;

    const size_t tile = (size_t)MTOT * HD;   // 4096*1024 floats = 16 MiB
    float* Q  = (float*)d_ws;
    float* Kb = Q + tile;
    float* Vb = Kb + tile;
    float* Ab = Q;          // alias: each attn block overwrites only the Q slice it read

    dim3 blk(256);
    dim3 gproj(HD / BN, MTOT / BM);          // (16, 64)
    gemm_bias_kernel<<<gproj, blk, 0, stream>>>(x, Wq, nullptr, Q,  MTOT, HD, DIMW);
    gemm_bias_kernel<<<gproj, blk, 0, stream>>>(x, Wk, nullptr, Kb, MTOT, HD, DIMW);
    gemm_bias_kernel<<<gproj, blk, 0, stream>>>(x, Wv, nullptr, Vb, MTOT, HD, DIMW);

    dim3 gattn(SEQ, NH, BATCH);              // (2048, 16, 2)
    attn_kernel<<<gattn, blk, 0, stream>>>(Q, Kb, Vb, Ab);

    dim3 gout(DIMW / BN, MTOT / BM);         // (16, 64)
    gemm_bias_kernel<<<gout, blk, 0, stream>>>(Ab, Wo, bo, out, MTOT, DIMW, HD);
}

// Round 2
// 725.273 us; speedup vs baseline: 10.9745x; 10.9745x over previous
//
#include <hip/hip_runtime.h>
#include <hip/hip_bf16.h>
#include <math.h>

#define DIMW   1024   // model dim
#define HD     1024   // n_heads * head_dim
#define NH     16
#define HDIM   64
#define SEQ    2048
#define BATCH  2
#define MTOT   (BATCH*SEQ)   // 4096

typedef __attribute__((ext_vector_type(8))) short short8;
typedef __attribute__((ext_vector_type(4))) float f32x4;

__device__ __forceinline__ ushort f2b(float f) {
    __hip_bfloat16 h = __float2bfloat16(f);   // RNE
    return *reinterpret_cast<ushort*>(&h);
}

// ---------------- fp32 tiled GEMM: C[M,N] = A[M,K] @ B[K,N] (+ bias) --------
// OT = float (fp32 out) or ushort (bf16 out, for Q/K/V feeding MFMA attention)
#define BM 64
#define BN 64
#define BK 16

template <typename OT>
__global__ __launch_bounds__(256) void gemm_bias_kernel(
    const float* __restrict__ A, const float* __restrict__ B,
    const float* __restrict__ bias, OT* __restrict__ C,
    int M, int N, int K)
{
    __shared__ float As[BK][BM + 1];
    __shared__ float Bs[BK][BN];

    const int tid = threadIdx.x;
    const int tx  = tid & 15;
    const int ty  = tid >> 4;
    const int n0  = blockIdx.x * BN;
    const int m0  = blockIdx.y * BM;

    float acc[4][4] = {};

    for (int k0 = 0; k0 < K; k0 += BK) {
        {
            const int k     = tid & 15;
            const int mbase = tid >> 4;
            #pragma unroll
            for (int j = 0; j < 4; ++j) {
                const int m = mbase + 16 * j;
                As[k][m] = A[(size_t)(m0 + m) * K + (k0 + k)];
            }
        }
        {
            const int n     = tid & 63;
            const int kbase = tid >> 6;
            #pragma unroll
            for (int j = 0; j < 4; ++j) {
                const int k = kbase + 4 * j;
                Bs[k][n] = B[(size_t)(k0 + k) * N + (n0 + n)];
            }
        }
        __syncthreads();

        #pragma unroll
        for (int kk = 0; kk < BK; ++kk) {
            float a[4], b[4];
            #pragma unroll
            for (int i = 0; i < 4; ++i) a[i] = As[kk][ty * 4 + i];
            #pragma unroll
            for (int j = 0; j < 4; ++j) b[j] = Bs[kk][tx * 4 + j];
            #pragma unroll
            for (int i = 0; i < 4; ++i)
                #pragma unroll
                for (int j = 0; j < 4; ++j)
                    acc[i][j] += a[i] * b[j];
        }
        __syncthreads();
    }

    #pragma unroll
    for (int i = 0; i < 4; ++i) {
        const int m = m0 + ty * 4 + i;
        #pragma unroll
        for (int j = 0; j < 4; ++j) {
            const int n = n0 + tx * 4 + j;
            float v = acc[i][j];
            if (bias) v += bias[n];
            if constexpr (sizeof(OT) == 2)
                C[(size_t)m * N + n] = f2b(v);
            else
                C[(size_t)m * N + n] = v;
        }
    }
}

// ---------------- flash attention, bf16 MFMA 16x16x32 -----------------------
// Block: 64 q-rows of one (b,h); 4 waves x 16 rows. Key tiles of 64.
// LDS: K tile [64 keys][64 d] bf16 (XOR-swizzled), V^T tile [64 d][64 keys],
//      P scratch (wave-private) for the S->A-fragment transpose.
// Fragment layouts (guide §3, m89-verified):
//   A frag: lane holds A[lane&15][ 8*(lane>>4) + j ], j=0..7 (8 contig bf16)
//   B frag: lane holds B[ 8*(lane>>4) + j ][lane&15]
//   C/D   : col = lane&15, row = (lane>>4)*4 + reg
__global__ __launch_bounds__(256) void flash_attn_kernel(
    const ushort* __restrict__ Q, const ushort* __restrict__ K,
    const ushort* __restrict__ V, float* __restrict__ Aout)
{
    __shared__ __align__(16) char KsB[64 * 128];   // 8 KB
    __shared__ __align__(16) char VtB[64 * 128];   // 8 KB
    __shared__ __align__(16) char PsB[4 * 2048];   // 8 KB (wave-private 2KB each)

    const int tid  = threadIdx.x;
    const int lane = tid & 63;
    const int w    = tid >> 6;       // wave 0..3
    const int lr   = lane & 15;
    const int lg   = lane >> 4;      // 0..3

    const int h  = blockIdx.y;
    const int b  = blockIdx.z;
    const int q0 = blockIdx.x * 64;

    // Q fragments for this wave's 16 rows (kept in registers all kernel)
    short8 qf[2];
    {
        const size_t base = (size_t)(b * SEQ + q0 + w * 16 + lr) * HD + h * HDIM;
        qf[0] = *(const short8*)(&Q[base + 0 * 32 + lg * 8]);
        qf[1] = *(const short8*)(&Q[base + 1 * 32 + lg * 8]);
    }

    f32x4 O[4];
    #pragma unroll
    for (int dn = 0; dn < 4; ++dn) O[dn] = f32x4{0.f, 0.f, 0.f, 0.f};
    float mo[4], li[4];
    #pragma unroll
    for (int r = 0; r < 4; ++r) { mo[r] = -1e30f; li[r] = 0.f; }

    const size_t kvbase = (size_t)(b * SEQ) * HD + h * HDIM;

    for (int kt = 0; kt < SEQ; kt += 64) {
        // ---- stage K tile (row-major, swizzled): 512 chunks of 16B
        #pragma unroll
        for (int i = 0; i < 2; ++i) {
            const int cid = tid + i * 256;
            const int row = cid >> 3, c = cid & 7;
            uint4 val = *(const uint4*)(&K[kvbase + (size_t)(kt + row) * HD + c * 8]);
            const int byte = (row * 128 + c * 16) ^ ((row & 7) << 4);
            *(uint4*)(&KsB[byte]) = val;
        }
        // ---- stage V transposed (Vt[d][key], swizzled)
        #pragma unroll
        for (int i = 0; i < 2; ++i) {
            const int cid = tid + i * 256;
            const int key = cid >> 3, c = cid & 7;
            uint4 val = *(const uint4*)(&V[kvbase + (size_t)(kt + key) * HD + c * 8]);
            const ushort* ve = (const ushort*)&val;
            #pragma unroll
            for (int j = 0; j < 8; ++j) {
                const int d = c * 8 + j;
                const int byte = (d * 128 + key * 2) ^ ((d & 7) << 4);
                *(ushort*)(&VtB[byte]) = ve[j];
            }
        }
        __syncthreads();

        // ---- S = Q K^T  (4 subtiles of 16 keys, K-dim 64 = 2 mfma steps)
        f32x4 S[4];
        #pragma unroll
        for (int sub = 0; sub < 4; ++sub) {
            f32x4 acc = {0.f, 0.f, 0.f, 0.f};
            #pragma unroll
            for (int s = 0; s < 2; ++s) {
                const int row  = sub * 16 + lr;
                const int byte = (row * 128 + (s * 4 + lg) * 16) ^ ((row & 7) << 4);
                short8 kf = *(const short8*)(&KsB[byte]);
                acc = __builtin_amdgcn_mfma_f32_16x16x32_bf16(qf[s], kf, acc, 0, 0, 0);
            }
            #pragma unroll
            for (int r = 0; r < 4; ++r) S[sub][r] = acc[r] * 0.125f;
        }

        // ---- online softmax: row = lg*4 + r, cols spread over lane&15
        float al[4];
        #pragma unroll
        for (int r = 0; r < 4; ++r) {
            float rm = fmaxf(fmaxf(S[0][r], S[1][r]), fmaxf(S[2][r], S[3][r]));
            rm = fmaxf(rm, __shfl_xor(rm, 1));
            rm = fmaxf(rm, __shfl_xor(rm, 2));
            rm = fmaxf(rm, __shfl_xor(rm, 4));
            rm = fmaxf(rm, __shfl_xor(rm, 8));
            const float mn = fmaxf(mo[r], rm);
            al[r] = __expf(mo[r] - mn);
            float rs = 0.f;
            #pragma unroll
            for (int sub = 0; sub < 4; ++sub) {
                const float p = __expf(S[sub][r] - mn);
                S[sub][r] = p;
                rs += p;
            }
            rs += __shfl_xor(rs, 1);
            rs += __shfl_xor(rs, 2);
            rs += __shfl_xor(rs, 4);
            rs += __shfl_xor(rs, 8);
            li[r] = li[r] * al[r] + rs;
            mo[r] = mn;
        }
        #pragma unroll
        for (int dn = 0; dn < 4; ++dn)
            #pragma unroll
            for (int r = 0; r < 4; ++r) O[dn][r] *= al[r];

        // ---- P -> LDS (wave-private, swizzled), then read back as A frags
        char* P = &PsB[w * 2048];
        #pragma unroll
        for (int sub = 0; sub < 4; ++sub)
            #pragma unroll
            for (int r = 0; r < 4; ++r) {
                const int row  = lg * 4 + r;
                const int col  = sub * 16 + lr;
                const int byte = (row * 128 + col * 2) ^ ((row & 7) << 4);
                *(ushort*)(&P[byte]) = f2b(S[sub][r]);
            }
        short8 pf[2];
        #pragma unroll
        for (int s = 0; s < 2; ++s) {
            const int byte = (lr * 128 + (s * 4 + lg) * 16) ^ ((lr & 7) << 4);
            pf[s] = *(const short8*)(&P[byte]);
        }

        // ---- O += P V   (4 d-subtiles x 2 k-steps)
        #pragma unroll
        for (int dn = 0; dn < 4; ++dn) {
            #pragma unroll
            for (int s = 0; s < 2; ++s) {
                const int row  = dn * 16 + lr;
                const int byte = (row * 128 + (s * 4 + lg) * 16) ^ ((row & 7) << 4);
                short8 vf = *(const short8*)(&VtB[byte]);
                O[dn] = __builtin_amdgcn_mfma_f32_16x16x32_bf16(pf[s], vf, O[dn], 0, 0, 0);
            }
        }
        __syncthreads();
    }

    // ---- epilogue: normalize, store fp32
    #pragma unroll
    for (int r = 0; r < 4; ++r) {
        const float inv = 1.f / li[r];
        const size_t base = (size_t)(b * SEQ + q0 + w * 16 + lg * 4 + r) * HD + h * HDIM;
        #pragma unroll
        for (int dn = 0; dn < 4; ++dn)
            Aout[base + dn * 16 + lr] = O[dn][r] * inv;
    }
}

// ---------------------------------------------------------------------------
extern "C" void kernel_launch(void* const* d_in, const int* in_sizes, int n_in,
                              void* d_out, int out_size, void* d_ws, size_t ws_size,
                              hipStream_t stream)
{
    const float* x  = (const float*)d_in[0];
    const float* Wq = (const float*)d_in[1];
    const float* Wk = (const float*)d_in[2];
    const float* Wv = (const float*)d_in[3];
    const float* Wo = (const float*)d_in[4];
    const float* bo = (const float*)d_in[5];
    float* out = (float*)d_out;

    // ws: Qb/Kb/Vb bf16 (8 MB each), Ab fp32 (16 MB) -> 40 MB total
    const size_t tile = (size_t)MTOT * HD;
    ushort* Qb = (ushort*)d_ws;
    ushort* Kb = Qb + tile;
    ushort* Vb = Kb + tile;
    float*  Ab = (float*)(Vb + tile);

    dim3 blk(256);
    dim3 gproj(HD / BN, MTOT / BM);
    gemm_bias_kernel<ushort><<<gproj, blk, 0, stream>>>(x, Wq, nullptr, Qb, MTOT, HD, DIMW);
    gemm_bias_kernel<ushort><<<gproj, blk, 0, stream>>>(x, Wk, nullptr, Kb, MTOT, HD, DIMW);
    gemm_bias_kernel<ushort><<<gproj, blk, 0, stream>>>(x, Wv, nullptr, Vb, MTOT, HD, DIMW);

    dim3 gattn(SEQ / 64, NH, BATCH);
    flash_attn_kernel<<<gattn, blk, 0, stream>>>(Qb, Kb, Vb, Ab);

    dim3 gout(DIMW / BN, MTOT / BM);
    gemm_bias_kernel<float><<<gout, blk, 0, stream>>>(Ab, Wo, bo, out, MTOT, DIMW, HD);
}

// Round 3
// 222.222 us; speedup vs baseline: 35.8180x; 3.2637x over previous
//
#include <hip/hip_runtime.h>
#include <hip/hip_bf16.h>
#include <math.h>

#define NH     16
#define HDIM   64
#define SEQ    2048
#define BATCH  2
#define MTOT   (BATCH*SEQ)   // 4096
#define DMODEL 1024
#define HD3    3072          // fused QKV width

typedef __attribute__((ext_vector_type(8))) short  short8;
typedef __attribute__((ext_vector_type(8))) ushort ushort8;
typedef __attribute__((ext_vector_type(4))) float  f32x4;

__device__ __forceinline__ ushort f2b(float f) {
    __hip_bfloat16 h = __float2bfloat16(f);   // RNE
    return *reinterpret_cast<ushort*>(&h);
}

// async global->LDS, 16B per lane; LDS dest = wave-uniform base + lane*16
__device__ __forceinline__ void gload_lds16(const void* g, void* l) {
    __builtin_amdgcn_global_load_lds(
        (const __attribute__((address_space(1))) unsigned int*)g,
        (__attribute__((address_space(3))) unsigned int*)l, 16, 0, 0);
}

// ---------------- fp32 -> bf16 convert (vectorized) -------------------------
__global__ __launch_bounds__(256) void cvt_f32_bf16_kernel(
    const float* __restrict__ in, ushort* __restrict__ out, int n8)
{
    const int i = blockIdx.x * 256 + threadIdx.x;
    if (i >= n8) return;
    const float4* p = (const float4*)(in + (size_t)i * 8);
    const float4 v0 = p[0], v1 = p[1];
    ushort8 o;
    o[0] = f2b(v0.x); o[1] = f2b(v0.y); o[2] = f2b(v0.z); o[3] = f2b(v0.w);
    o[4] = f2b(v1.x); o[5] = f2b(v1.y); o[6] = f2b(v1.z); o[7] = f2b(v1.w);
    *(ushort8*)(out + (size_t)i * 8) = o;
}

// ---------------- W [1024][1024] f32  ->  Wt [1024][1024] bf16 (transposed) --
__global__ __launch_bounds__(256) void transpose_w_kernel(
    const float* __restrict__ W, ushort* __restrict__ Wt)
{
    __shared__ float s[64][33];          // [n][k], +1 pad
    const int tid = threadIdx.x;
    const int k0  = blockIdx.y * 32;
    const int n0  = blockIdx.x * 64;
    #pragma unroll
    for (int i = 0; i < 8; ++i) {
        const int idx = tid + i * 256;   // 0..2047
        const int n = idx & 63, k = idx >> 6;
        s[n][k] = W[(size_t)(k0 + k) * DMODEL + n0 + n];
    }
    __syncthreads();
    const int n  = tid >> 2;
    const int kc = (tid & 3) * 8;
    ushort8 o;
    #pragma unroll
    for (int j = 0; j < 8; ++j) o[j] = f2b(s[n][kc + j]);
    *(ushort8*)(&Wt[(size_t)(n0 + n) * DMODEL + k0 + kc]) = o;
}

// ---------------- bf16 MFMA GEMM: C[M,N] = A[M,K] @ Bt[N,K]^T (+bias) -------
// m97 structure: 128x128 tile, BK=32, 4 waves (2x2), 4x4 16x16x32 frags/wave.
// LDS tiles [128 rows][32 bf16], chunk-swizzled cc ^= (row>>1)&3 (involution):
// applied on the global SOURCE for gload_lds (linear dest) and on ds_read.
template <typename OT>
__global__ __launch_bounds__(256) void gemm_mfma_kernel(
    const ushort* __restrict__ A,    // [M][K] bf16
    const ushort* __restrict__ Bt,   // [N][K] bf16
    const float* __restrict__ bias,  // len N, or null
    OT* __restrict__ C,              // [M][N]
    int M, int N, int K)
{
    __shared__ __align__(16) ushort As[128 * 32];   // 8 KB
    __shared__ __align__(16) ushort Bs[128 * 32];   // 8 KB

    const int tid  = threadIdx.x;
    const int lane = tid & 63;
    const int lr   = lane & 15;
    const int lg   = lane >> 4;
    const int w    = tid >> 6;
    const int wm   = w >> 1, wn = w & 1;

    const int m0 = blockIdx.y * 128;
    const int n0 = blockIdx.x * 128;

    f32x4 acc[4][4];
    #pragma unroll
    for (int mi = 0; mi < 4; ++mi)
        #pragma unroll
        for (int ni = 0; ni < 4; ++ni) acc[mi][ni] = f32x4{0.f, 0.f, 0.f, 0.f};

    for (int kt = 0; kt < K; kt += 32) {
        #pragma unroll
        for (int i = 0; i < 2; ++i) {
            const int ch  = i * 256 + tid;           // chunk 0..511 (16B each)
            const int row = ch >> 2;
            const int ccd = ch & 3;
            const int ccs = ccd ^ ((row >> 1) & 3);  // pre-swizzled source
            gload_lds16(&A [(size_t)(m0 + row) * K + kt + ccs * 8], &As[ch * 8]);
            gload_lds16(&Bt[(size_t)(n0 + row) * K + kt + ccs * 8], &Bs[ch * 8]);
        }
        __syncthreads();

        short8 af[4], bf[4];
        #pragma unroll
        for (int mi = 0; mi < 4; ++mi) {
            const int row = wm * 64 + mi * 16 + lr;
            af[mi] = *(const short8*)(&As[row * 32 + (lg ^ ((row >> 1) & 3)) * 8]);
        }
        #pragma unroll
        for (int ni = 0; ni < 4; ++ni) {
            const int row = wn * 64 + ni * 16 + lr;
            bf[ni] = *(const short8*)(&Bs[row * 32 + (lg ^ ((row >> 1) & 3)) * 8]);
        }
        #pragma unroll
        for (int mi = 0; mi < 4; ++mi)
            #pragma unroll
            for (int ni = 0; ni < 4; ++ni)
                acc[mi][ni] = __builtin_amdgcn_mfma_f32_16x16x32_bf16(
                    af[mi], bf[ni], acc[mi][ni], 0, 0, 0);
        __syncthreads();
    }

    #pragma unroll
    for (int mi = 0; mi < 4; ++mi) {
        #pragma unroll
        for (int ni = 0; ni < 4; ++ni) {
            const int n = n0 + wn * 64 + ni * 16 + lr;
            const float bv = bias ? bias[n] : 0.f;
            #pragma unroll
            for (int r = 0; r < 4; ++r) {
                const int m = m0 + wm * 64 + mi * 16 + lg * 4 + r;
                const float v = acc[mi][ni][r] + bv;
                if constexpr (sizeof(OT) == 2)
                    C[(size_t)m * N + n] = f2b(v);
                else
                    C[(size_t)m * N + n] = v;
            }
        }
    }
}

// ---------------- flash attention, bf16 MFMA 16x16x32 -----------------------
// QKV fused buffer [MTOT][3072]: Q at +0, K at +1024, V at +2048 (per row).
// Output Aout bf16 [MTOT][1024].
__global__ __launch_bounds__(256) void flash_attn_kernel(
    const ushort* __restrict__ QKV, ushort* __restrict__ Aout)
{
    __shared__ __align__(16) char KsB[64 * 128];   // 8 KB
    __shared__ __align__(16) char VtB[64 * 128];   // 8 KB (V^T [d][key])
    __shared__ __align__(16) char PsB[4 * 2048];   // 8 KB wave-private

    const int tid  = threadIdx.x;
    const int lane = tid & 63;
    const int w    = tid >> 6;
    const int lr   = lane & 15;
    const int lg   = lane >> 4;

    const int h  = blockIdx.y;
    const int b  = blockIdx.z;
    const int q0 = blockIdx.x * 64;

    short8 qf[2];
    {
        const size_t base = (size_t)(b * SEQ + q0 + w * 16 + lr) * HD3 + h * HDIM;
        qf[0] = *(const short8*)(&QKV[base + 0]);
        qf[1] = *(const short8*)(&QKV[base + 32 + lg * 8 - lg * 8 + 32]);  // placeholder fix below
    }
    // (re-load correctly: k-offset = s*32 + lg*8)
    {
        const size_t base = (size_t)(b * SEQ + q0 + w * 16 + lr) * HD3 + h * HDIM;
        qf[0] = *(const short8*)(&QKV[base + 0 * 32 + lg * 8]);
        qf[1] = *(const short8*)(&QKV[base + 1 * 32 + lg * 8]);
    }

    f32x4 O[4];
    #pragma unroll
    for (int dn = 0; dn < 4; ++dn) O[dn] = f32x4{0.f, 0.f, 0.f, 0.f};
    float mo[4], li[4];
    #pragma unroll
    for (int r = 0; r < 4; ++r) { mo[r] = -1e30f; li[r] = 0.f; }

    const size_t kbase = (size_t)(b * SEQ) * HD3 + 1024 + h * HDIM;
    const size_t vbase = (size_t)(b * SEQ) * HD3 + 2048 + h * HDIM;

    for (int kt = 0; kt < SEQ; kt += 64) {
        // ---- stage K tile row-major, swizzled (coalesced-ish 16B chunks)
        #pragma unroll
        for (int i = 0; i < 2; ++i) {
            const int cid = tid + i * 256;
            const int row = cid >> 3, c = cid & 7;
            uint4 val = *(const uint4*)(&QKV[kbase + (size_t)(kt + row) * HD3 + c * 8]);
            const int byte = (row * 128 + c * 16) ^ ((row & 7) << 4);
            *(uint4*)(&KsB[byte]) = val;
        }
        // ---- stage V^T [d][key], conflict-free writes: key = lane
        #pragma unroll
        for (int i = 0; i < 2; ++i) {
            const int cid = tid + i * 256;
            const int key = cid & 63;
            const int c   = cid >> 6;                // 0..7
            uint4 val = *(const uint4*)(&QKV[vbase + (size_t)(kt + key) * HD3 + c * 8]);
            const ushort* ve = (const ushort*)&val;
            #pragma unroll
            for (int j = 0; j < 8; ++j) {
                const int d    = c * 8 + j;
                const int byte = (d * 128 + key * 2) ^ ((d & 7) << 4);
                *(ushort*)(&VtB[byte]) = ve[j];
            }
        }
        __syncthreads();

        // ---- S = Q K^T
        f32x4 S[4];
        #pragma unroll
        for (int sub = 0; sub < 4; ++sub) {
            f32x4 acc = {0.f, 0.f, 0.f, 0.f};
            #pragma unroll
            for (int s = 0; s < 2; ++s) {
                const int row  = sub * 16 + lr;
                const int byte = (row * 128 + (s * 4 + lg) * 16) ^ ((row & 7) << 4);
                short8 kf = *(const short8*)(&KsB[byte]);
                acc = __builtin_amdgcn_mfma_f32_16x16x32_bf16(qf[s], kf, acc, 0, 0, 0);
            }
            #pragma unroll
            for (int r = 0; r < 4; ++r) S[sub][r] = acc[r] * 0.125f;
        }

        // ---- online softmax (rows = lg*4 + r, cols over lane&15)
        float al[4];
        #pragma unroll
        for (int r = 0; r < 4; ++r) {
            float rm = fmaxf(fmaxf(S[0][r], S[1][r]), fmaxf(S[2][r], S[3][r]));
            rm = fmaxf(rm, __shfl_xor(rm, 1));
            rm = fmaxf(rm, __shfl_xor(rm, 2));
            rm = fmaxf(rm, __shfl_xor(rm, 4));
            rm = fmaxf(rm, __shfl_xor(rm, 8));
            const float mn = fmaxf(mo[r], rm);
            al[r] = __expf(mo[r] - mn);
            float rs = 0.f;
            #pragma unroll
            for (int sub = 0; sub < 4; ++sub) {
                const float p = __expf(S[sub][r] - mn);
                S[sub][r] = p;
                rs += p;
            }
            rs += __shfl_xor(rs, 1);
            rs += __shfl_xor(rs, 2);
            rs += __shfl_xor(rs, 4);
            rs += __shfl_xor(rs, 8);
            li[r] = li[r] * al[r] + rs;
            mo[r] = mn;
        }
        #pragma unroll
        for (int dn = 0; dn < 4; ++dn)
            #pragma unroll
            for (int r = 0; r < 4; ++r) O[dn][r] *= al[r];

        // ---- P -> LDS (wave-private, swizzled), read back as A frags
        char* P = &PsB[w * 2048];
        #pragma unroll
        for (int sub = 0; sub < 4; ++sub)
            #pragma unroll
            for (int r = 0; r < 4; ++r) {
                const int row  = lg * 4 + r;
                const int col  = sub * 16 + lr;
                const int byte = (row * 128 + col * 2) ^ ((row & 7) << 4);
                *(ushort*)(&P[byte]) = f2b(S[sub][r]);
            }
        short8 pf[2];
        #pragma unroll
        for (int s = 0; s < 2; ++s) {
            const int byte = (lr * 128 + (s * 4 + lg) * 16) ^ ((lr & 7) << 4);
            pf[s] = *(const short8*)(&P[byte]);
        }

        // ---- O += P V
        #pragma unroll
        for (int dn = 0; dn < 4; ++dn) {
            #pragma unroll
            for (int s = 0; s < 2; ++s) {
                const int row  = dn * 16 + lr;
                const int byte = (row * 128 + (s * 4 + lg) * 16) ^ ((row & 7) << 4);
                short8 vf = *(const short8*)(&VtB[byte]);
                O[dn] = __builtin_amdgcn_mfma_f32_16x16x32_bf16(pf[s], vf, O[dn], 0, 0, 0);
            }
        }
        __syncthreads();
    }

    // ---- epilogue: normalize, store bf16 into [MTOT][1024]
    #pragma unroll
    for (int r = 0; r < 4; ++r) {
        const float inv = 1.f / li[r];
        const size_t base = (size_t)(b * SEQ + q0 + w * 16 + lg * 4 + r) * DMODEL + h * HDIM;
        #pragma unroll
        for (int dn = 0; dn < 4; ++dn)
            Aout[base + dn * 16 + lr] = f2b(O[dn][r] * inv);
    }
}

// ---------------------------------------------------------------------------
extern "C" void kernel_launch(void* const* d_in, const int* in_sizes, int n_in,
                              void* d_out, int out_size, void* d_ws, size_t ws_size,
                              hipStream_t stream)
{
    const float* x  = (const float*)d_in[0];
    const float* Wq = (const float*)d_in[1];
    const float* Wk = (const float*)d_in[2];
    const float* Wv = (const float*)d_in[3];
    const float* Wo = (const float*)d_in[4];
    const float* bo = (const float*)d_in[5];
    float* out = (float*)d_out;

    // ws: xb 8MB | Wt_qkv 6MB | Wot 2MB | QKV 24MB    (Ab aliases xb)
    ushort* xb  = (ushort*)d_ws;
    ushort* Wt  = xb  + (size_t)MTOT * DMODEL;
    ushort* Wot = Wt  + (size_t)HD3  * DMODEL;
    ushort* QKV = Wot + (size_t)DMODEL * DMODEL;
    ushort* Ab  = xb;   // x dead after QKV projection

    dim3 blk(256);

    cvt_f32_bf16_kernel<<<dim3(MTOT * DMODEL / 8 / 256), blk, 0, stream>>>(
        x, xb, MTOT * DMODEL / 8);

    dim3 gtr(16, 32);
    transpose_w_kernel<<<gtr, blk, 0, stream>>>(Wq, Wt);
    transpose_w_kernel<<<gtr, blk, 0, stream>>>(Wk, Wt + (size_t)1024 * 1024);
    transpose_w_kernel<<<gtr, blk, 0, stream>>>(Wv, Wt + (size_t)2048 * 1024);
    transpose_w_kernel<<<gtr, blk, 0, stream>>>(Wo, Wot);

    gemm_mfma_kernel<ushort><<<dim3(HD3 / 128, MTOT / 128), blk, 0, stream>>>(
        xb, Wt, nullptr, QKV, MTOT, HD3, DMODEL);

    flash_attn_kernel<<<dim3(SEQ / 64, NH, BATCH), blk, 0, stream>>>(QKV, Ab);

    gemm_mfma_kernel<float><<<dim3(DMODEL / 128, MTOT / 128), blk, 0, stream>>>(
        Ab, Wot, bo, out, MTOT, DMODEL, DMODEL);
}

// Round 4
// 183.512 us; speedup vs baseline: 43.3733x; 1.2109x over previous
//
#include <hip/hip_runtime.h>
#include <hip/hip_bf16.h>
#include <math.h>

#define NH     16
#define HDIM   64
#define SEQ    2048
#define BATCH  2
#define MTOT   (BATCH*SEQ)   // 4096
#define DMODEL 1024
#define HD3    3072          // fused QKV width

typedef __attribute__((ext_vector_type(8))) short  short8;
typedef __attribute__((ext_vector_type(8))) ushort ushort8;
typedef __attribute__((ext_vector_type(4))) ushort ushortx4;
typedef __attribute__((ext_vector_type(4))) float  f32x4;

__device__ __forceinline__ ushort f2b(float f) {
    __hip_bfloat16 h = __float2bfloat16(f);   // RNE
    return *reinterpret_cast<ushort*>(&h);
}
__device__ __forceinline__ uint pack2(float a, float b) {
    return (uint)f2b(a) | ((uint)f2b(b) << 16);
}

// async global->LDS, 16B per lane; LDS dest = wave-uniform base + lane*16
__device__ __forceinline__ void gload_lds16(const void* g, void* l) {
    __builtin_amdgcn_global_load_lds(
        (const __attribute__((address_space(1))) unsigned int*)g,
        (__attribute__((address_space(3))) unsigned int*)l, 16, 0, 0);
}

// ---------------- fp32 -> bf16 convert (vectorized) -------------------------
__global__ __launch_bounds__(256) void cvt_f32_bf16_kernel(
    const float* __restrict__ in, ushort* __restrict__ out, int n8)
{
    const int i = blockIdx.x * 256 + threadIdx.x;
    if (i >= n8) return;
    const float4* p = (const float4*)(in + (size_t)i * 8);
    const float4 v0 = p[0], v1 = p[1];
    ushort8 o;
    o[0] = f2b(v0.x); o[1] = f2b(v0.y); o[2] = f2b(v0.z); o[3] = f2b(v0.w);
    o[4] = f2b(v1.x); o[5] = f2b(v1.y); o[6] = f2b(v1.z); o[7] = f2b(v1.w);
    *(ushort8*)(out + (size_t)i * 8) = o;
}

// ---------------- W [1024][1024] f32  ->  Wt [1024][1024] bf16 (transposed) --
__global__ __launch_bounds__(256) void transpose_w_kernel(
    const float* __restrict__ W, ushort* __restrict__ Wt)
{
    __shared__ float s[64][33];
    const int tid = threadIdx.x;
    const int k0  = blockIdx.y * 32;
    const int n0  = blockIdx.x * 64;
    #pragma unroll
    for (int i = 0; i < 8; ++i) {
        const int idx = tid + i * 256;
        const int n = idx & 63, k = idx >> 6;
        s[n][k] = W[(size_t)(k0 + k) * DMODEL + n0 + n];
    }
    __syncthreads();
    const int n  = tid >> 2;
    const int kc = (tid & 3) * 8;
    ushort8 o;
    #pragma unroll
    for (int j = 0; j < 8; ++j) o[j] = f2b(s[n][kc + j]);
    *(ushort8*)(&Wt[(size_t)(n0 + n) * DMODEL + k0 + kc]) = o;
}

// ---------------- bf16 MFMA GEMM: C[M,N] = A[M,K] @ Bt[N,K]^T (+bias) -------
template <typename OT>
__global__ __launch_bounds__(256) void gemm_mfma_kernel(
    const ushort* __restrict__ A, const ushort* __restrict__ Bt,
    const float* __restrict__ bias, OT* __restrict__ C,
    int M, int N, int K)
{
    __shared__ __align__(16) ushort As[128 * 32];
    __shared__ __align__(16) ushort Bs[128 * 32];

    const int tid  = threadIdx.x;
    const int lane = tid & 63;
    const int lr   = lane & 15;
    const int lg   = lane >> 4;
    const int w    = tid >> 6;
    const int wm   = w >> 1, wn = w & 1;

    const int m0 = blockIdx.y * 128;
    const int n0 = blockIdx.x * 128;

    f32x4 acc[4][4];
    #pragma unroll
    for (int mi = 0; mi < 4; ++mi)
        #pragma unroll
        for (int ni = 0; ni < 4; ++ni) acc[mi][ni] = f32x4{0.f, 0.f, 0.f, 0.f};

    for (int kt = 0; kt < K; kt += 32) {
        #pragma unroll
        for (int i = 0; i < 2; ++i) {
            const int ch  = i * 256 + tid;
            const int row = ch >> 2;
            const int ccd = ch & 3;
            const int ccs = ccd ^ ((row >> 1) & 3);
            gload_lds16(&A [(size_t)(m0 + row) * K + kt + ccs * 8], &As[ch * 8]);
            gload_lds16(&Bt[(size_t)(n0 + row) * K + kt + ccs * 8], &Bs[ch * 8]);
        }
        __syncthreads();

        short8 af[4], bf[4];
        #pragma unroll
        for (int mi = 0; mi < 4; ++mi) {
            const int row = wm * 64 + mi * 16 + lr;
            af[mi] = *(const short8*)(&As[row * 32 + (lg ^ ((row >> 1) & 3)) * 8]);
        }
        #pragma unroll
        for (int ni = 0; ni < 4; ++ni) {
            const int row = wn * 64 + ni * 16 + lr;
            bf[ni] = *(const short8*)(&Bs[row * 32 + (lg ^ ((row >> 1) & 3)) * 8]);
        }
        #pragma unroll
        for (int mi = 0; mi < 4; ++mi)
            #pragma unroll
            for (int ni = 0; ni < 4; ++ni)
                acc[mi][ni] = __builtin_amdgcn_mfma_f32_16x16x32_bf16(
                    af[mi], bf[ni], acc[mi][ni], 0, 0, 0);
        __syncthreads();
    }

    #pragma unroll
    for (int mi = 0; mi < 4; ++mi) {
        #pragma unroll
        for (int ni = 0; ni < 4; ++ni) {
            const int n = n0 + wn * 64 + ni * 16 + lr;
            const float bv = bias ? bias[n] : 0.f;
            #pragma unroll
            for (int r = 0; r < 4; ++r) {
                const int m = m0 + wm * 64 + mi * 16 + lg * 4 + r;
                const float v = acc[mi][ni][r] + bv;
                if constexpr (sizeof(OT) == 2)
                    C[(size_t)m * N + n] = f2b(v);
                else
                    C[(size_t)m * N + n] = v;
            }
        }
    }
}

// ---------------- flash attention, swapped-QK^T bf16 MFMA -------------------
// Block: 64 q-rows of one (b,h); 4 waves x 16 rows; 64-key tiles.
// S^T = mfma(K_frag, Q_frag): lane owns q-row (lane&15); keys 16*sub+4*lg+r.
// Softmax lane-local (in-reg 16 + shfl_xor 16,32). P^T regrouped in-register
// to the PV B-frag (keys 8*lg+j) via 8 shfl + 4 cndmask per k-step.
// O^T = mfma(V^T_frag, P^T_frag): lane holds O[d = dn*16+4*lg+r][q = lane&15].
// K/V tile prefetched to regs one tile ahead (T14 async-stage split).
__global__ __launch_bounds__(256) void flash_attn_kernel(
    const ushort* __restrict__ QKV, ushort* __restrict__ Aout)
{
    __shared__ __align__(16) char KsB[64 * 128];   // 8 KB, XOR-swizzled
    __shared__ __align__(16) char VtB[64 * 128];   // 8 KB, V^T [d][key] swizzled

    const int tid  = threadIdx.x;
    const int lane = tid & 63;
    const int w    = tid >> 6;
    const int lr   = lane & 15;
    const int lg   = lane >> 4;
    const bool hi  = lg >= 2;

    const int h  = blockIdx.y;
    const int b  = blockIdx.z;
    const int q0 = blockIdx.x * 64;

    // Q fragments (B-operand of swapped QK^T): lane holds Q[q0+w*16+lr][s*32+lg*8+j]
    const size_t qrow = (size_t)(b * SEQ + q0 + w * 16 + lr);
    short8 qf[2];
    qf[0] = *(const short8*)(&QKV[qrow * HD3 + h * HDIM + 0 * 32 + lg * 8]);
    qf[1] = *(const short8*)(&QKV[qrow * HD3 + h * HDIM + 1 * 32 + lg * 8]);

    f32x4 O[4];
    #pragma unroll
    for (int dn = 0; dn < 4; ++dn) O[dn] = f32x4{0.f, 0.f, 0.f, 0.f};
    float mo = -1e30f, li = 0.f;

    const size_t kbase = (size_t)(b * SEQ) * HD3 + 1024 + h * HDIM;
    const size_t vbase = (size_t)(b * SEQ) * HD3 + 2048 + h * HDIM;

    // staging geometry (per thread, fixed)
    const int rk0 = tid >> 3,          ck0 = tid & 7;          // K chunk 0
    const int rk1 = (tid + 256) >> 3,  ck1 = (tid + 256) & 7;  // K chunk 1
    const int kv0 = tid & 63,          cv0 = tid >> 6;         // V chunk 0
    const int kv1 = (tid + 256) & 63,  cv1 = (tid + 256) >> 6; // V chunk 1

    // prologue prefetch (tile 0)
    uint4 kpre0 = *(const uint4*)(&QKV[kbase + (size_t)(0 + rk0) * HD3 + ck0 * 8]);
    uint4 kpre1 = *(const uint4*)(&QKV[kbase + (size_t)(0 + rk1) * HD3 + ck1 * 8]);
    uint4 vpre0 = *(const uint4*)(&QKV[vbase + (size_t)(0 + kv0) * HD3 + cv0 * 8]);
    uint4 vpre1 = *(const uint4*)(&QKV[vbase + (size_t)(0 + kv1) * HD3 + cv1 * 8]);

    const int srcA = lr + 16 * ((2 * lg) & 3);
    const int srcB = lr + 16 * ((2 * lg + 1) & 3);

    for (int kt = 0; kt < SEQ; kt += 64) {
        // ---- write staged regs -> LDS
        {
            const int by0 = (rk0 * 128 + ck0 * 16) ^ ((rk0 & 7) << 4);
            const int by1 = (rk1 * 128 + ck1 * 16) ^ ((rk1 & 7) << 4);
            *(uint4*)(&KsB[by0]) = kpre0;
            *(uint4*)(&KsB[by1]) = kpre1;
            const ushort* ve0 = (const ushort*)&vpre0;
            const ushort* ve1 = (const ushort*)&vpre1;
            #pragma unroll
            for (int j = 0; j < 8; ++j) {   // d&7 == j  (d = cv*8 + j)
                const int d0 = cv0 * 8 + j, d1 = cv1 * 8 + j;
                *(ushort*)(&VtB[(d0 * 128 + kv0 * 2) ^ (j << 4)]) = ve0[j];
                *(ushort*)(&VtB[(d1 * 128 + kv1 * 2) ^ (j << 4)]) = ve1[j];
            }
        }
        __syncthreads();

        // ---- issue next-tile prefetch (lands during compute below)
        {
            const int ktn = (kt + 64 < SEQ) ? kt + 64 : 0;   // clamp (dummy reload)
            kpre0 = *(const uint4*)(&QKV[kbase + (size_t)(ktn + rk0) * HD3 + ck0 * 8]);
            kpre1 = *(const uint4*)(&QKV[kbase + (size_t)(ktn + rk1) * HD3 + ck1 * 8]);
            vpre0 = *(const uint4*)(&QKV[vbase + (size_t)(ktn + kv0) * HD3 + cv0 * 8]);
            vpre1 = *(const uint4*)(&QKV[vbase + (size_t)(ktn + kv1) * HD3 + cv1 * 8]);
        }

        // ---- S^T = K Q^T : p[sub][r] = score(key=16*sub+4*lg+r, q=lr)
        float p[4][4];
        #pragma unroll
        for (int sub = 0; sub < 4; ++sub) {
            f32x4 acc = {0.f, 0.f, 0.f, 0.f};
            #pragma unroll
            for (int s = 0; s < 2; ++s) {
                const int row  = sub * 16 + lr;
                const int byte = (row * 128 + (s * 4 + lg) * 16) ^ ((row & 7) << 4);
                short8 kf = *(const short8*)(&KsB[byte]);
                acc = __builtin_amdgcn_mfma_f32_16x16x32_bf16(kf, qf[s], acc, 0, 0, 0);
            }
            #pragma unroll
            for (int r = 0; r < 4; ++r) p[sub][r] = acc[r] * 0.125f;
        }

        // ---- lane-local online softmax (q = lane&15; keys split over lg)
        float rm = p[0][0];
        #pragma unroll
        for (int sub = 0; sub < 4; ++sub)
            #pragma unroll
            for (int r = 0; r < 4; ++r) rm = fmaxf(rm, p[sub][r]);
        rm = fmaxf(rm, __shfl_xor(rm, 16));
        rm = fmaxf(rm, __shfl_xor(rm, 32));
        const float mn = fmaxf(mo, rm);
        const float al = __expf(mo - mn);
        float rs = 0.f;
        #pragma unroll
        for (int sub = 0; sub < 4; ++sub)
            #pragma unroll
            for (int r = 0; r < 4; ++r) {
                const float e = __expf(p[sub][r] - mn);
                p[sub][r] = e;
                rs += e;
            }
        rs += __shfl_xor(rs, 16);
        rs += __shfl_xor(rs, 32);
        li = li * al + rs;
        mo = mn;
        #pragma unroll
        for (int dn = 0; dn < 4; ++dn)
            #pragma unroll
            for (int r = 0; r < 4; ++r) O[dn][r] *= al;

        // ---- regroup P^T into PV B-frags (keys s*32+8*lg+j per lane)
        short8 pf[2];
        #pragma unroll
        for (int s = 0; s < 2; ++s) {
            const uint P01e = pack2(p[2*s+0][0], p[2*s+0][1]);
            const uint P23e = pack2(p[2*s+0][2], p[2*s+0][3]);
            const uint P01o = pack2(p[2*s+1][0], p[2*s+1][1]);
            const uint P23o = pack2(p[2*s+1][2], p[2*s+1][3]);
            const uint a0 = (uint)__shfl((int)P01e, srcA);
            const uint a1 = (uint)__shfl((int)P01o, srcA);
            const uint b0 = (uint)__shfl((int)P23e, srcA);
            const uint b1 = (uint)__shfl((int)P23o, srcA);
            const uint c0 = (uint)__shfl((int)P01e, srcB);
            const uint c1 = (uint)__shfl((int)P01o, srcB);
            const uint d0 = (uint)__shfl((int)P23e, srcB);
            const uint d1 = (uint)__shfl((int)P23o, srcB);
            union { short8 v; uint u[4]; } un;
            un.u[0] = hi ? a1 : a0;
            un.u[1] = hi ? b1 : b0;
            un.u[2] = hi ? c1 : c0;
            un.u[3] = hi ? d1 : d0;
            pf[s] = un.v;
        }

        // ---- O^T += V^T P^T
        #pragma unroll
        for (int dn = 0; dn < 4; ++dn) {
            #pragma unroll
            for (int s = 0; s < 2; ++s) {
                const int row  = dn * 16 + lr;
                const int byte = (row * 128 + (s * 4 + lg) * 16) ^ ((row & 7) << 4);
                short8 vf = *(const short8*)(&VtB[byte]);
                O[dn] = __builtin_amdgcn_mfma_f32_16x16x32_bf16(vf, pf[s], O[dn], 0, 0, 0);
            }
        }
        __syncthreads();
    }

    // ---- epilogue: O^T lane holds q=lane&15, d = dn*16 + lg*4 + r
    const float inv = 1.f / li;
    const size_t obase = qrow * DMODEL + h * HDIM;
    #pragma unroll
    for (int dn = 0; dn < 4; ++dn) {
        ushortx4 o;
        #pragma unroll
        for (int r = 0; r < 4; ++r) o[r] = f2b(O[dn][r] * inv);
        *(ushortx4*)(&Aout[obase + dn * 16 + lg * 4]) = o;
    }
}

// ---------------------------------------------------------------------------
extern "C" void kernel_launch(void* const* d_in, const int* in_sizes, int n_in,
                              void* d_out, int out_size, void* d_ws, size_t ws_size,
                              hipStream_t stream)
{
    const float* x  = (const float*)d_in[0];
    const float* Wq = (const float*)d_in[1];
    const float* Wk = (const float*)d_in[2];
    const float* Wv = (const float*)d_in[3];
    const float* Wo = (const float*)d_in[4];
    const float* bo = (const float*)d_in[5];
    float* out = (float*)d_out;

    // ws: xb 8MB | Wt_qkv 6MB | Wot 2MB | QKV 24MB    (Ab aliases xb)
    ushort* xb  = (ushort*)d_ws;
    ushort* Wt  = xb  + (size_t)MTOT * DMODEL;
    ushort* Wot = Wt  + (size_t)HD3  * DMODEL;
    ushort* QKV = Wot + (size_t)DMODEL * DMODEL;
    ushort* Ab  = xb;   // x dead after QKV projection

    dim3 blk(256);

    cvt_f32_bf16_kernel<<<dim3(MTOT * DMODEL / 8 / 256), blk, 0, stream>>>(
        x, xb, MTOT * DMODEL / 8);

    dim3 gtr(16, 32);
    transpose_w_kernel<<<gtr, blk, 0, stream>>>(Wq, Wt);
    transpose_w_kernel<<<gtr, blk, 0, stream>>>(Wk, Wt + (size_t)1024 * 1024);
    transpose_w_kernel<<<gtr, blk, 0, stream>>>(Wv, Wt + (size_t)2048 * 1024);
    transpose_w_kernel<<<gtr, blk, 0, stream>>>(Wo, Wot);

    gemm_mfma_kernel<ushort><<<dim3(HD3 / 128, MTOT / 128), blk, 0, stream>>>(
        xb, Wt, nullptr, QKV, MTOT, HD3, DMODEL);

    flash_attn_kernel<<<dim3(SEQ / 64, NH, BATCH), blk, 0, stream>>>(QKV, Ab);

    gemm_mfma_kernel<float><<<dim3(DMODEL / 128, MTOT / 128), blk, 0, stream>>>(
        Ab, Wot, bo, out, MTOT, DMODEL, DMODEL);
}